// Round 10
// baseline (272.628 us; speedup 1.0000x reference)
//
#include <hip/hip_runtime.h>
#include <math.h>

#define ROWS 16
#define NPAIRS 195
#define NTHREADS 256
#define ROW_OUT 258            // 63 copied + 195 distances
#define NLM 21
#define TILE_F (ROWS * ROW_OUT)   // 4128 floats = 16512 B
#define IN_F (ROWS * 63)          // 1008 floats
#define GRID 1024                 // 4 blocks/CU on 256 CUs

typedef float f32x4 __attribute__((ext_vector_type(4)));

// barrier with LDS-only drain: do NOT wait for outstanding global (nt) stores
#define LDS_BARRIER() asm volatile("s_waitcnt lgkmcnt(0)\n\ts_barrier" ::: "memory")

// ---- compile-time pair table, packed as (i | j<<16) ----
struct CodeTab { unsigned int c[NPAIRS]; };

constexpr CodeTab make_codes() {
    CodeTab t{};
    int n = 0;
    for (int a = 0; a < 20; ++a) {
        bool tip = (a == 4) || (a == 8) || (a == 12) || (a == 16) || (a == 19);
        int start = tip ? a + 1 : a + 2;
        for (int b = start; b < 21; ++b) {
            t.c[n] = (unsigned int)a | ((unsigned int)b << 16);
            ++n;
        }
    }
    return t;
}

__constant__ CodeTab CODES = make_codes();

// thread t<252 owns column col = t%63 of rows r0, r0+4, r0+8, r0+12 (r0 = t/63).
// col/lm/c3 computed ONCE; all LDS writes lane-stride 4B (conflict-free).
__device__ __forceinline__ void scatter_tile(float* __restrict__ tile,
                                             float2* __restrict__ xy2,
                                             const float v[4], int r0, int col,
                                             int lm, int c3) {
#pragma unroll
    for (int e = 0; e < 4; ++e) {
        tile[(r0 + 4 * e) * ROW_OUT + col] = v[e];
    }
    if (c3 == 0) {
#pragma unroll
        for (int e = 0; e < 4; ++e) xy2[(r0 + 4 * e) * NLM + lm].x = v[e];
    } else if (c3 == 1) {
#pragma unroll
        for (int e = 0; e < 4; ++e) xy2[(r0 + 4 * e) * NLM + lm].y = v[e];
    }
}

// row-grouped: r = t>>4 (16 rows x 16-lane groups), p = q + 16k
__device__ __forceinline__ void compute_dists(float* __restrict__ tile,
                                              const float2* __restrict__ xy2,
                                              int t) {
    const int r = t >> 4;
    const int q = t & 15;
    const float2* __restrict__ xr = xy2 + r * NLM;
    float* __restrict__ drow = tile + r * ROW_OUT + 63;
#pragma unroll
    for (int k = 0; k < 13; ++k) {
        const int p = q + (k << 4);
        if (k < 12 || q < 3) {              // p < 195
            const unsigned int c = CODES.c[p];
            const float2 a = xr[c & 0xffu];
            const float2 b = xr[c >> 16];
            const float dx = a.x - b.x;
            const float dy = a.y - b.y;
            drow[p] = __builtin_amdgcn_sqrtf(dx * dx + dy * dy);
        }
    }
}

// in : [B, 63]  (21 landmarks x (x,y,z))
// out: [B, 258] = [copy of 63 | 195 pairwise 2D distances]
__global__ __launch_bounds__(NTHREADS)
void HandKineticLayer_18545668784560_kernel(const float* __restrict__ in,
                                            float* __restrict__ out,
                                            int B) {
    __shared__ __align__(16) float tile[2][TILE_F];
    __shared__ float2 xy2[2][ROWS * NLM];

    const int t = threadIdx.x;
    const int ntiles = B / ROWS;               // full tiles

    // per-thread load geometry (t < 252): hoisted once
    const int r0 = t / 63;
    const int col = t - r0 * 63;
    const int lm = col / 3;
    const int c3 = col - lm * 3;

    // ---- prologue: load + scatter first tile into buffer 0 ----
    const int tile0 = blockIdx.x;
    if (tile0 < ntiles) {
        if (t < 252) {
            const float* __restrict__ ip = in + (size_t)tile0 * IN_F + t;
            float v[4];
#pragma unroll
            for (int e = 0; e < 4; ++e)
                v[e] = __builtin_nontemporal_load(ip + 252 * e);
            scatter_tile(tile[0], xy2[0], v, r0, col, lm, c3);
        }
        LDS_BARRIER();
    }

    // ---- pipelined main loop: prefetch(k+1) || compute(k); store(k); scatter(k+1) ----
    int i = 0;
    for (int tl = tile0; tl < ntiles; tl += GRID, ++i) {
        const int cur = i & 1;
        const int nxt = tl + GRID;
        float vn[4] = {0.f, 0.f, 0.f, 0.f};
        const bool have_next = (nxt < ntiles) && (t < 252);
        if (have_next) {
            const float* __restrict__ ip = in + (size_t)nxt * IN_F + t;
#pragma unroll
            for (int e = 0; e < 4; ++e)
                vn[e] = __builtin_nontemporal_load(ip + 252 * e);   // in flight during compute+store
        }

        compute_dists(tile[cur], xy2[cur], t);
        LDS_BARRIER();     // dists visible before store reads (LDS only)

        {
            const f32x4* __restrict__ tl4 =
                reinterpret_cast<const f32x4*>(&tile[cur][0]);
            f32x4* __restrict__ o4 =
                reinterpret_cast<f32x4*>(out + (size_t)tl * TILE_F);
#pragma unroll
            for (int k = t; k < TILE_F / 4; k += NTHREADS) {
                __builtin_nontemporal_store(tl4[k], &o4[k]);
            }
        }

        if (have_next) {
            scatter_tile(tile[cur ^ 1], xy2[cur ^ 1], vn, r0, col, lm, c3);
        }
        LDS_BARRIER();     // scatter visible; store's LDS reads of cur drained
    }

    // ---- tail: partial tile (B % 16 != 0), one block, non-pipelined ----
    const int rem = B - ntiles * ROWS;
    if (rem > 0 && blockIdx.x == (unsigned)(ntiles % GRID)) {
        const int rowBase = ntiles * ROWS;
        const int nelem = rem * 63;
        for (int g = t; g < nelem; g += NTHREADS) {
            const float val = in[(size_t)rowBase * 63 + g];
            const int row = g / 63;
            const int cc = g - row * 63;
            tile[0][row * ROW_OUT + cc] = val;
            const int lmm = cc / 3;
            const int cc3 = cc - lmm * 3;
            if (cc3 == 0) xy2[0][row * NLM + lmm].x = val;
            else if (cc3 == 1) xy2[0][row * NLM + lmm].y = val;
        }
        __syncthreads();
        const int total = rem * NPAIRS;
        for (int idx = t; idx < total; idx += NTHREADS) {
            const int row = idx / NPAIRS;
            const int p = idx - row * NPAIRS;
            const unsigned int c = CODES.c[p];
            const float2 a = xy2[0][row * NLM + (int)(c & 0xffu)];
            const float2 b = xy2[0][row * NLM + (int)(c >> 16)];
            const float dx = a.x - b.x;
            const float dy = a.y - b.y;
            tile[0][row * ROW_OUT + 63 + p] = __builtin_amdgcn_sqrtf(dx * dx + dy * dy);
        }
        __syncthreads();
        const int nout = rem * ROW_OUT;
        for (int k = t; k < nout; k += NTHREADS) {
            out[(size_t)rowBase * ROW_OUT + k] = tile[0][k];
        }
    }
}

extern "C" void kernel_launch(void* const* d_in, const int* in_sizes, int n_in,
                              void* d_out, int out_size, void* d_ws, size_t ws_size,
                              hipStream_t stream) {
    const float* in = (const float*)d_in[0];
    float* out = (float*)d_out;
    const int B = in_sizes[0] / 63;
    hipLaunchKernelGGL(HandKineticLayer_18545668784560_kernel,
                       dim3(GRID), dim3(NTHREADS), 0, stream,
                       in, out, B);
}

// Round 12
// 256.887 us; speedup vs baseline: 1.0613x; 1.0613x over previous
//
#include <hip/hip_runtime.h>
#include <math.h>

#define ROWS 16
#define NPAIRS 195
#define NTHREADS 256
#define ROW_OUT 258            // 63 copied + 195 distances
#define NLM 21
#define TILE_F (ROWS * ROW_OUT)   // 4128 floats = 16512 B
#define IN_F (ROWS * 63)          // 1008 floats
#define GRID 2048                 // 8 blocks/CU on 256 CUs (single-buffer LDS)

typedef float f32x4 __attribute__((ext_vector_type(4)));

// ---- compile-time pair table, packed as (i | j<<16) ----
struct CodeTab { unsigned int c[NPAIRS]; };

constexpr CodeTab make_codes() {
    CodeTab t{};
    int n = 0;
    for (int a = 0; a < 20; ++a) {
        bool tip = (a == 4) || (a == 8) || (a == 12) || (a == 16) || (a == 19);
        int start = tip ? a + 1 : a + 2;
        for (int b = start; b < 21; ++b) {
            t.c[n] = (unsigned int)a | ((unsigned int)b << 16);
            ++n;
        }
    }
    return t;
}

__constant__ CodeTab CODES = make_codes();

// thread t<252 owns column col = t%63 of rows r0, r0+4, r0+8, r0+12 (r0 = t/63).
// col/lm/c3 computed ONCE; all LDS writes lane-stride 4B (conflict-free).
__device__ __forceinline__ void scatter_tile(float* __restrict__ tile,
                                             float2* __restrict__ xy2,
                                             const float v[4], int r0, int col,
                                             int lm, int c3) {
#pragma unroll
    for (int e = 0; e < 4; ++e) {
        tile[(r0 + 4 * e) * ROW_OUT + col] = v[e];
    }
    if (c3 == 0) {
#pragma unroll
        for (int e = 0; e < 4; ++e) xy2[(r0 + 4 * e) * NLM + lm].x = v[e];
    } else if (c3 == 1) {
#pragma unroll
        for (int e = 0; e < 4; ++e) xy2[(r0 + 4 * e) * NLM + lm].y = v[e];
    }
}

// row-grouped: r = t>>4 (16 rows x 16-lane groups), p = q + 16k
__device__ __forceinline__ void compute_dists(float* __restrict__ tile,
                                              const float2* __restrict__ xy2,
                                              int t) {
    const int r = t >> 4;
    const int q = t & 15;
    const float2* __restrict__ xr = xy2 + r * NLM;
    float* __restrict__ drow = tile + r * ROW_OUT + 63;
#pragma unroll
    for (int k = 0; k < 13; ++k) {
        const int p = q + (k << 4);
        if (k < 12 || q < 3) {              // p < 195
            const unsigned int c = CODES.c[p];
            const float2 a = xr[c & 0xffu];
            const float2 b = xr[c >> 16];
            const float dx = a.x - b.x;
            const float dy = a.y - b.y;
            drow[p] = __builtin_amdgcn_sqrtf(dx * dx + dy * dy);
        }
    }
}

// in : [B, 63]  (21 landmarks x (x,y,z))
// out: [B, 258] = [copy of 63 | 195 pairwise 2D distances]
__global__ __launch_bounds__(NTHREADS, 8)
void HandKineticLayer_18545668784560_kernel(const float* __restrict__ in,
                                            float* __restrict__ out,
                                            int B) {
    // SINGLE buffer: next tile is prefetched into registers; LDS reuse is
    // protected by the 3 __syncthreads() below. 19.2 KB/block -> 8 blocks/CU.
    __shared__ __align__(16) float tile[TILE_F];
    __shared__ float2 xy2[ROWS * NLM];

    const int t = threadIdx.x;
    const int ntiles = B / ROWS;               // full tiles

    // per-thread load geometry (t < 252): hoisted once
    const int r0 = t / 63;
    const int col = t - r0 * 63;
    const int lm = col / 3;
    const int c3 = col - lm * 3;

    // ---- prologue: load + scatter first tile ----
    const int tile0 = blockIdx.x;
    if (tile0 < ntiles) {
        if (t < 252) {
            const float* __restrict__ ip = in + (size_t)tile0 * IN_F + t;
            float v[4];
#pragma unroll
            for (int e = 0; e < 4; ++e)
                v[e] = __builtin_nontemporal_load(ip + 252 * e);
            scatter_tile(tile, xy2, v, r0, col, lm, c3);
        }
        __syncthreads();
    }

    // ---- main loop: prefetch(k+1)->regs || compute(k); store(k); scatter(k+1) ----
    for (int tl = tile0; tl < ntiles; tl += GRID) {
        const int nxt = tl + GRID;
        float vn[4] = {0.f, 0.f, 0.f, 0.f};
        const bool have_next = (nxt < ntiles) && (t < 252);
        if (have_next) {
            const float* __restrict__ ip = in + (size_t)nxt * IN_F + t;
#pragma unroll
            for (int e = 0; e < 4; ++e)
                vn[e] = __builtin_nontemporal_load(ip + 252 * e);
        }

        compute_dists(tile, xy2, t);
        __syncthreads();   // dists visible before store reads

        {
            const f32x4* __restrict__ tl4 =
                reinterpret_cast<const f32x4*>(&tile[0]);
            f32x4* __restrict__ o4 =
                reinterpret_cast<f32x4*>(out + (size_t)tl * TILE_F);
#pragma unroll
            for (int k = t; k < TILE_F / 4; k += NTHREADS) {
                __builtin_nontemporal_store(tl4[k], &o4[k]);
            }
        }
        __syncthreads();   // all waves done READING tile before overwrite

        if (have_next) {
            scatter_tile(tile, xy2, vn, r0, col, lm, c3);
        }
        __syncthreads();   // scatter visible for next compute
    }

    // ---- tail: partial tile (B % 16 != 0), one block, non-pipelined ----
    const int rem = B - ntiles * ROWS;
    if (rem > 0 && blockIdx.x == (unsigned)(ntiles % GRID)) {
        const int rowBase = ntiles * ROWS;
        const int nelem = rem * 63;
        for (int g = t; g < nelem; g += NTHREADS) {
            const float val = in[(size_t)rowBase * 63 + g];
            const int row = g / 63;
            const int cc = g - row * 63;
            tile[row * ROW_OUT + cc] = val;
            const int lmm = cc / 3;
            const int cc3 = cc - lmm * 3;
            if (cc3 == 0) xy2[row * NLM + lmm].x = val;
            else if (cc3 == 1) xy2[row * NLM + lmm].y = val;
        }
        __syncthreads();
        const int total = rem * NPAIRS;
        for (int idx = t; idx < total; idx += NTHREADS) {
            const int row = idx / NPAIRS;
            const int p = idx - row * NPAIRS;
            const unsigned int c = CODES.c[p];
            const float2 a = xy2[row * NLM + (int)(c & 0xffu)];
            const float2 b = xy2[row * NLM + (int)(c >> 16)];
            const float dx = a.x - b.x;
            const float dy = a.y - b.y;
            tile[row * ROW_OUT + 63 + p] = __builtin_amdgcn_sqrtf(dx * dx + dy * dy);
        }
        __syncthreads();
        const int nout = rem * ROW_OUT;
        for (int k = t; k < nout; k += NTHREADS) {
            out[(size_t)rowBase * ROW_OUT + k] = tile[k];
        }
    }
}

extern "C" void kernel_launch(void* const* d_in, const int* in_sizes, int n_in,
                              void* d_out, int out_size, void* d_ws, size_t ws_size,
                              hipStream_t stream) {
    const float* in = (const float*)d_in[0];
    float* out = (float*)d_out;
    const int B = in_sizes[0] / 63;
    hipLaunchKernelGGL(HandKineticLayer_18545668784560_kernel,
                       dim3(GRID), dim3(NTHREADS), 0, stream,
                       in, out, B);
}